// Round 8
// baseline (379.297 us; speedup 1.0000x reference)
//
#include <hip/hip_runtime.h>
#include <hip/hip_bf16.h>
#include <math.h>

#define N_TOK 2048
#define H_DIM 1024
#define N_EXP 16
#define I_DIM 768
#define TOPK 4
#define SCALE 2.5f
#define MAX_TILES 96

typedef __attribute__((ext_vector_type(8))) short bf16x8;
typedef __attribute__((ext_vector_type(4))) float f32x4;

// workspace layout (bytes)
#define OFF_COUNTS   0
#define OFF_OFFSETS  128
#define OFF_TILES    256
#define OFF_TOKIDS   768
#define OFF_TOKW     (OFF_TOKIDS + N_EXP*N_TOK*4)
#define OFF_XB       (OFF_TOKW + N_EXP*N_TOK*4)
#define OFF_HACT     (OFF_XB + (size_t)N_TOK*H_DIM*2)
#define OFF_GWT      (OFF_HACT + (size_t)N_TOK*(TOPK+1)*I_DIM*2)
// total ~20.3 MB

__device__ __forceinline__ ushort f2bf(float f) {
    union { __hip_bfloat16 h; ushort u; } cv;
    cv.h = __float2bfloat16(f);
    return cv.u;
}
__device__ __forceinline__ unsigned pack2(float lo, float hi) {
    return (unsigned)f2bf(lo) | ((unsigned)f2bf(hi) << 16);
}
__device__ __forceinline__ void async_copy16(const void* g, void* l) {
    __builtin_amdgcn_global_load_lds(
        (const __attribute__((address_space(1))) unsigned int*)g,
        (__attribute__((address_space(3))) unsigned int*)l, 16, 0, 0);
}
__device__ __forceinline__ uint4 pack8(float4 a, float4 b) {
    uint4 p;
    p.x = pack2(a.x, a.y); p.y = pack2(a.z, a.w);
    p.z = pack2(b.x, b.y); p.w = pack2(b.z, b.w);
    return p;
}

// ---------------- x -> bf16 (4 MB write; weights are converted in-GEMM now) ----------------
__global__ void k_xconv(const float* __restrict__ x, ushort* __restrict__ xb) {
    int idx = (blockIdx.x * 256 + threadIdx.x) * 8;
    float4 a = *(const float4*)(x + idx);
    float4 b = *(const float4*)(x + idx + 4);
    *(uint4*)(xb + idx) = pack8(a, b);
}

// ---------------- gate_w transpose: gwT[k][e] (fp32, 64 KB, stays cache-hot) ----------------
__global__ void k_gwt(const float* __restrict__ gw, float* __restrict__ gwT) {
    int i = blockIdx.x * 256 + threadIdx.x;   // 16384 elements
    int k = i >> 4, e = i & 15;
    gwT[i] = gw[e * H_DIM + k];
}

// ---------------- routing: 1 wave/token, lane = (kslice, expert) ----------------
__launch_bounds__(256)
__global__ void k_route(const float* __restrict__ x, const float* __restrict__ gwT,
                        const float* __restrict__ gb,
                        int* __restrict__ counts, int* __restrict__ tok_ids,
                        float* __restrict__ tok_w) {
    __shared__ float lgs[4][N_EXP + 1];
    int tid = threadIdx.x;
    int wv = tid >> 6, lane = tid & 63;
    int e = lane & 15, ks = lane >> 4;        // expert, k-slice (4 x 256)
    int n = blockIdx.x * 4 + wv;

    const float* xr = x + (size_t)n * H_DIM + ks * 256;      // broadcast over 16 e-lanes
    const float* wr = gwT + ks * 256 * N_EXP + e;            // contiguous over e-lanes
    float a0 = 0.f, a1 = 0.f, a2 = 0.f, a3 = 0.f;
#pragma unroll 8
    for (int k = 0; k < 256; k += 4) {
        float4 xv = *(const float4*)(xr + k);
        a0 += xv.x * wr[(k + 0) * N_EXP];
        a1 += xv.y * wr[(k + 1) * N_EXP];
        a2 += xv.z * wr[(k + 2) * N_EXP];
        a3 += xv.w * wr[(k + 3) * N_EXP];
    }
    float acc = (a0 + a1) + (a2 + a3);
    acc += __shfl_xor(acc, 16);   // fold k-slices
    acc += __shfl_xor(acc, 32);
    if (lane < 16) lgs[wv][lane] = acc;
    __syncthreads();

    if (tid < 4) {
        int n2 = blockIdx.x * 4 + tid;
        float sc[N_EXP], sb[N_EXP];
        for (int ee = 0; ee < N_EXP; ee++) {
            float l = lgs[tid][ee];
            sc[ee] = 1.f / (1.f + expf(-l));
            sb[ee] = sc[ee] + gb[ee];
        }
        float gsc[4];
        for (int g = 0; g < 4; g++) {
            float m1 = -1e30f, m2 = -1e30f;
            for (int j = 0; j < 4; j++) {
                float v = sb[4 * g + j];
                if (v > m1) { m2 = m1; m1 = v; }
                else if (v > m2) m2 = v;
            }
            gsc[g] = m1 + m2;
        }
        int g1 = 0;
        for (int g = 1; g < 4; g++) if (gsc[g] > gsc[g1]) g1 = g;
        int g2 = -1;
        for (int g = 0; g < 4; g++) {
            if (g == g1) continue;
            if (g2 < 0 || gsc[g] > gsc[g2]) g2 = g;
        }
        bool allowed[N_EXP];
        for (int ee = 0; ee < N_EXP; ee++) {
            int grp = ee >> 2;
            allowed[ee] = (grp == g1) || (grp == g2);
        }
        int chosen[TOPK];
        float wsum = 0.f;
        for (int k = 0; k < TOPK; k++) {
            int best = -1;
            for (int ee = 0; ee < N_EXP; ee++) {
                if (!allowed[ee]) continue;
                if (best < 0 || sb[ee] > sb[best]) best = ee;
            }
            chosen[k] = best;
            allowed[best] = false;
            wsum += sc[best];
        }
        float inv = SCALE / (wsum + 1e-20f);
        for (int k = 0; k < TOPK; k++) {
            int ee = chosen[k];
            int p = atomicAdd(&counts[ee], 1);
            tok_ids[ee * N_TOK + p] = n2;
            tok_w[ee * N_TOK + p] = sc[ee] * inv;
        }
    }
}

// ---------------- scan + tile-descriptor compaction ----------------
__global__ void k_scan(const int* __restrict__ counts, int* __restrict__ offsets,
                       int* __restrict__ tiles) {
    if (threadIdx.x == 0 && blockIdx.x == 0) {
        int off = 0;
        for (int e = 0; e < N_EXP; e++) { offsets[e] = off; off += counts[e]; }
        offsets[N_EXP] = off;  // shared expert base (= 8192)
        int t = 0;
        for (int e = 0; e < N_EXP; e++)
            for (int m0 = 0; m0 < counts[e]; m0 += 128)
                tiles[t++] = e | ((m0 >> 7) << 5);
        for (int m0 = 0; m0 < N_TOK; m0 += 128)
            tiles[t++] = N_EXP | ((m0 >> 7) << 5);
        for (; t < MAX_TILES; t++) tiles[t] = -1;
    }
}

// ---------------- stage A: gate/up proj + silu, gathered ----------------
// M=128, N=128 merged [w1|w3], BK=64; A via global_load_lds, B fp32->bf16
// register-pipelined staging (load k+1 regs during MFMA phase of k).
__launch_bounds__(256, 4)
__global__ void k_gateup(const ushort* __restrict__ xb, const float* __restrict__ w1,
                         const float* __restrict__ w3, const float* __restrict__ ws1,
                         const float* __restrict__ ws3, const int* __restrict__ counts,
                         const int* __restrict__ offsets, const int* __restrict__ tiles,
                         const int* __restrict__ tok_ids, const float* __restrict__ tok_w,
                         ushort* __restrict__ hact) {
    int desc = tiles[blockIdx.x];
    if (desc < 0) return;
    int e = desc & 31;
    int m0 = (desc >> 5) * 128;
    int i0 = blockIdx.y * 64;
    int Me = (e == N_EXP) ? N_TOK : counts[e];
    const float* W1 = (e == N_EXP) ? ws1 : w1 + (size_t)e * I_DIM * H_DIM;
    const float* W3 = (e == N_EXP) ? ws3 : w3 + (size_t)e * I_DIM * H_DIM;
    int base = offsets[e];

    __shared__ ushort As[128][64];
    __shared__ ushort Bs[128][64];   // rows 0-63: w1, rows 64-127: w3
    __shared__ float tws[128];

    int tid = threadIdx.x;
    int wv = tid >> 6, lane = tid & 63;
    int seg = lane & 7, rsub = lane >> 3;
    int gch = (seg ^ rsub) * 8;   // swizzled source chunk (element offset)

    if (tid < 128) {
        int r = m0 + tid;
        tws[tid] = (e == N_EXP) ? 1.f : ((r < Me) ? tok_w[e * N_TOK + r] : 0.f);
    }

    const ushort* aptr[4];
#pragma unroll
    for (int j = 0; j < 4; j++) {
        int gr = m0 + wv * 32 + j * 8 + rsub;
        int tok = (e == N_EXP) ? gr : ((gr < Me) ? tok_ids[e * N_TOK + gr] : 0);
        aptr[j] = xb + (size_t)tok * H_DIM + gch;
    }
    const float* bptr[4];
#pragma unroll
    for (int j = 0; j < 4; j++) {
        int r = wv * 32 + j * 8 + rsub;  // 0..127 (wave-uniform W1/W3 split per j)
        const float* W = (r < 64) ? (W1 + (size_t)(i0 + r) * H_DIM)
                                  : (W3 + (size_t)(i0 + r - 64) * H_DIM);
        bptr[j] = W + gch;
    }

    int quad = lane >> 4, lr = lane & 15, rx = lr & 7;
    f32x4 acc[2][8] = {};
    float4 bv[4][2];

    // prologue: B(0) into regs
#pragma unroll
    for (int j = 0; j < 4; j++) {
        bv[j][0] = *(const float4*)(bptr[j]);
        bv[j][1] = *(const float4*)(bptr[j] + 4);
    }

    const int NK = H_DIM / 64;
    for (int k = 0; k < NK; k++) {
        int off = k * 64;
        // pack B(k) regs -> LDS (conflict-free: lanes cover 1024 consecutive bytes)
#pragma unroll
        for (int j = 0; j < 4; j++)
            *(uint4*)&Bs[wv * 32 + j * 8 + rsub][seg * 8] = pack8(bv[j][0], bv[j][1]);
#pragma unroll
        for (int j = 0; j < 4; j++) async_copy16(aptr[j] + off, &As[wv * 32 + j * 8][0]);
        __syncthreads();
        if (k + 1 < NK) {   // B(k+1) regs in flight across the MFMA phase
            int o2 = off + 64;
#pragma unroll
            for (int j = 0; j < 4; j++) {
                bv[j][0] = *(const float4*)(bptr[j] + o2);
                bv[j][1] = *(const float4*)(bptr[j] + o2 + 4);
            }
        }
#pragma unroll
        for (int ks = 0; ks < 2; ks++) {
            int co = ((ks * 4 + quad) ^ rx) * 8;  // swizzled read chunk
            bf16x8 a0 = *(const bf16x8*)&As[wv * 32 + lr][co];
            bf16x8 a1 = *(const bf16x8*)&As[wv * 32 + 16 + lr][co];
#pragma unroll
            for (int ni = 0; ni < 8; ni++) {
                bf16x8 bf = *(const bf16x8*)&Bs[ni * 16 + lr][co];
                acc[0][ni] = __builtin_amdgcn_mfma_f32_16x16x32_bf16(a0, bf, acc[0][ni], 0, 0, 0);
                acc[1][ni] = __builtin_amdgcn_mfma_f32_16x16x32_bf16(a1, bf, acc[1][ni], 0, 0, 0);
            }
        }
        __syncthreads();
    }

    // epilogue: g = acc[.][0..3], u = acc[.][4..7] (same lane) -> silu(g)*u*tw
#pragma unroll
    for (int mi = 0; mi < 2; mi++) {
#pragma unroll
        for (int ni = 0; ni < 4; ni++) {
            f32x4 g = acc[mi][ni];
            f32x4 u = acc[mi][ni + 4];
#pragma unroll
            for (int rg = 0; rg < 4; rg++) {
                int ml = wv * 32 + mi * 16 + quad * 4 + rg;
                int row = m0 + ml;
                if (row < Me) {
                    float gg = g[rg], uu = u[rg];
                    float act = (gg / (1.f + expf(-gg))) * uu * tws[ml];
                    hact[(size_t)(base + row) * I_DIM + i0 + ni * 16 + lr] = f2bf(act);
                }
            }
        }
    }
}

// ---------------- stage B: down proj + scatter-add ----------------
// M=128 slots, N=128 of H, BK=64 over I=768; same pipelined fp32-B staging.
__launch_bounds__(256, 4)
__global__ void k_down(const ushort* __restrict__ hact, const float* __restrict__ w2,
                       const float* __restrict__ ws2, const int* __restrict__ counts,
                       const int* __restrict__ offsets, const int* __restrict__ tiles,
                       const int* __restrict__ tok_ids, float* __restrict__ out) {
    int desc = tiles[blockIdx.x];
    if (desc < 0) return;
    int e = desc & 31;
    int m0 = (desc >> 5) * 128;
    int h0 = blockIdx.y * 128;
    int Me = (e == N_EXP) ? N_TOK : counts[e];
    const float* W2 = (e == N_EXP) ? ws2 : w2 + (size_t)e * H_DIM * I_DIM;
    int base = offsets[e];

    __shared__ ushort As[128][64];
    __shared__ ushort Bs[128][64];
    __shared__ int toks[128];

    int tid = threadIdx.x;
    int wv = tid >> 6, lane = tid & 63;
    int seg = lane & 7, rsub = lane >> 3;
    int gch = (seg ^ rsub) * 8;

    if (tid < 128) {
        int r = m0 + tid;
        toks[tid] = (e == N_EXP) ? r : ((r < Me) ? tok_ids[e * N_TOK + r] : 0);
    }

    const ushort* aptr[4];
#pragma unroll
    for (int j = 0; j < 4; j++) {
        int row = wv * 32 + j * 8 + rsub;
        aptr[j] = hact + (size_t)(base + m0 + row) * I_DIM + gch;
    }
    const float* bptr[4];
#pragma unroll
    for (int j = 0; j < 4; j++) {
        int r = wv * 32 + j * 8 + rsub;
        bptr[j] = W2 + (size_t)(h0 + r) * I_DIM + gch;
    }

    int quad = lane >> 4, lr = lane & 15, rx = lr & 7;
    f32x4 acc[2][8] = {};
    float4 bv[4][2];

#pragma unroll
    for (int j = 0; j < 4; j++) {
        bv[j][0] = *(const float4*)(bptr[j]);
        bv[j][1] = *(const float4*)(bptr[j] + 4);
    }

    const int NK = I_DIM / 64;
    for (int k = 0; k < NK; k++) {
        int off = k * 64;
#pragma unroll
        for (int j = 0; j < 4; j++)
            *(uint4*)&Bs[wv * 32 + j * 8 + rsub][seg * 8] = pack8(bv[j][0], bv[j][1]);
#pragma unroll
        for (int j = 0; j < 4; j++) async_copy16(aptr[j] + off, &As[wv * 32 + j * 8][0]);
        __syncthreads();
        if (k + 1 < NK) {
            int o2 = off + 64;
#pragma unroll
            for (int j = 0; j < 4; j++) {
                bv[j][0] = *(const float4*)(bptr[j] + o2);
                bv[j][1] = *(const float4*)(bptr[j] + o2 + 4);
            }
        }
#pragma unroll
        for (int ks = 0; ks < 2; ks++) {
            int co = ((ks * 4 + quad) ^ rx) * 8;
            bf16x8 a0 = *(const bf16x8*)&As[wv * 32 + lr][co];
            bf16x8 a1 = *(const bf16x8*)&As[wv * 32 + 16 + lr][co];
#pragma unroll
            for (int ni = 0; ni < 8; ni++) {
                bf16x8 bf = *(const bf16x8*)&Bs[ni * 16 + lr][co];
                acc[0][ni] = __builtin_amdgcn_mfma_f32_16x16x32_bf16(a0, bf, acc[0][ni], 0, 0, 0);
                acc[1][ni] = __builtin_amdgcn_mfma_f32_16x16x32_bf16(a1, bf, acc[1][ni], 0, 0, 0);
            }
        }
        __syncthreads();
    }

#pragma unroll
    for (int mi = 0; mi < 2; mi++) {
#pragma unroll
        for (int ni = 0; ni < 8; ni++) {
#pragma unroll
            for (int rg = 0; rg < 4; rg++) {
                int ml = wv * 32 + mi * 16 + quad * 4 + rg;
                int row = m0 + ml;
                if (row < Me) {
                    int tok = toks[ml];
                    atomicAdd(&out[(size_t)tok * H_DIM + h0 + ni * 16 + lr],
                              acc[mi][ni][rg]);
                }
            }
        }
    }
}

extern "C" void kernel_launch(void* const* d_in, const int* in_sizes, int n_in,
                              void* d_out, int out_size, void* d_ws, size_t ws_size,
                              hipStream_t stream) {
    const float* x   = (const float*)d_in[0];
    const float* gw  = (const float*)d_in[1];
    const float* gb  = (const float*)d_in[2];
    const float* w1  = (const float*)d_in[3];
    const float* w2  = (const float*)d_in[4];
    const float* w3  = (const float*)d_in[5];
    const float* ws1 = (const float*)d_in[6];
    const float* ws2 = (const float*)d_in[7];
    const float* ws3 = (const float*)d_in[8];
    float* out = (float*)d_out;

    char* wsb = (char*)d_ws;
    int* counts   = (int*)(wsb + OFF_COUNTS);
    int* offsets  = (int*)(wsb + OFF_OFFSETS);
    int* tiles    = (int*)(wsb + OFF_TILES);
    int* tok_ids  = (int*)(wsb + OFF_TOKIDS);
    float* tok_w  = (float*)(wsb + OFF_TOKW);
    ushort* xb    = (ushort*)(wsb + OFF_XB);
    ushort* hact  = (ushort*)(wsb + OFF_HACT);
    float* gwT    = (float*)(wsb + OFF_GWT);

    hipMemsetAsync(wsb, 0, 128, stream);                       // counts
    hipMemsetAsync(d_out, 0, (size_t)out_size * 4, stream);    // zero outputs

    k_xconv<<<N_TOK * H_DIM / (256 * 8), 256, 0, stream>>>(x, xb);
    k_gwt<<<N_EXP * H_DIM / 256, 256, 0, stream>>>(gw, gwT);
    k_route<<<N_TOK / 4, 256, 0, stream>>>(x, gwT, gb, counts, tok_ids, tok_w);
    k_scan<<<1, 1, 0, stream>>>(counts, offsets, tiles);
    {
        dim3 grid(MAX_TILES, I_DIM / 64);
        k_gateup<<<grid, 256, 0, stream>>>(xb, w1, w3, ws1, ws3, counts, offsets,
                                           tiles, tok_ids, tok_w, hact);
    }
    {
        dim3 grid(MAX_TILES, H_DIM / 128);
        k_down<<<grid, 256, 0, stream>>>(hact, w2, ws2, counts, offsets, tiles,
                                         tok_ids, out);
    }
}